// Round 5
// baseline (155.711 us; speedup 1.0000x reference)
//
#include <hip/hip_runtime.h>
#include <math.h>

#define B_ 64
#define S_ 512
#define N_ 24
#define H_ 768
#define C_ 6
#define CHUNKS 16                        // blocks per batch
#define TOK_PER_BLOCK (S_ / CHUNKS)      // 32 tokens per block
#define TOK_PER_WAVE (TOK_PER_BLOCK / 4) // 8 contiguous tokens per wave
#define NC (N_ * C_)                     // 144

// Arrival counters for the last-block-per-batch finalize. Zero-initialized at
// module load; the finalizing block re-arms its counter to 0 every launch, so
// the protocol survives graph replay. __device__ memory: untouched by the
// harness's workspace poison.
__device__ int g_cnt[B_];

// Single fused dispatch, 1024 blocks (256 CU x 2 resident + 2 queued: the
// oversubscription is worth ~4-5us vs a single 512-block cohort — measured
// round 0 vs round 4). Per block: stream 32 tokens with the proven 112-VGPR
// inner loop (register-pinned W fragment, 24-deep float4 prefetch, ballot
// segment-id, LDS lane-partial accumulators), reduce to 144 partials, publish
// via device-scope atomicExch, count arrivals; the 16th block of each batch
// reads the partials back with coherent atomicAdd(p,0) reads and finalizes.
// DO NOT tighten the occupancy bound: this loop needs ~112 VGPRs; any cap
// below that spills x[8][3] to scratch (round 2: 290us, round 3: 75us).
__global__ __launch_bounds__(256, 2) void seg_proj_fused(
    const float* __restrict__ lhs, const int* __restrict__ st,
    const float* __restrict__ W, const float* __restrict__ bias,
    float* __restrict__ ws, float* __restrict__ out) {
  __shared__ float acc[NC * 64];  // 36 KB
  __shared__ int s_old;
  const int tid = threadIdx.x;
  const int lane = tid & 63;
  const int wave = tid >> 6;
  const int b = blockIdx.x >> 4;       // CHUNKS == 16
  const int chunk = blockIdx.x & 15;

  // zero LDS accumulators (2304 float4s / 256 threads = 9 each)
  float4* accv = (float4*)acc;
#pragma unroll
  for (int i = 0; i < 9; ++i)
    accv[i * 256 + tid] = make_float4(0.f, 0.f, 0.f, 0.f);

  // boundaries resident in lanes (sentinel for lanes >= 24)
  int stb_l = (lane < N_) ? st[b * N_ + lane] : 0x7fffffff;
  // tokens s > min(last_boundary, 500) are provably discarded downstream:
  //   s > last -> past the final segment (never flushed);
  //   s > 500  -> its segment has end >= s > 500 -> override in finalize.
  // Non-overridden segments have end <= min(last,500), so every token they
  // need satisfies s <= lim and its wave is never skipped.
  const int last = __shfl(stb_l, N_ - 1);
  const int lim = last > 500 ? 500 : last;

  // W fragment: lane holds W[c][k*256 + lane*4 .. +3], k=0..2, c=0..5 (72 VGPRs)
  const float4* W4 = (const float4*)W;
  float4 w[3][C_];
#pragma unroll
  for (int k = 0; k < 3; ++k)
#pragma unroll
    for (int c = 0; c < C_; ++c)
      w[k][c] = W4[c * (H_ / 4) + k * 64 + lane];
  // pin: forbid rematerialization of the W loads
#pragma unroll
  for (int k = 0; k < 3; ++k)
    asm volatile("" : "+v"(w[k][0].x), "+v"(w[k][0].y), "+v"(w[k][0].z), "+v"(w[k][0].w),
                       "+v"(w[k][1].x), "+v"(w[k][1].y), "+v"(w[k][1].z), "+v"(w[k][1].w),
                       "+v"(w[k][2].x), "+v"(w[k][2].y), "+v"(w[k][2].z), "+v"(w[k][2].w),
                       "+v"(w[k][3].x), "+v"(w[k][3].y), "+v"(w[k][3].z), "+v"(w[k][3].w),
                       "+v"(w[k][4].x), "+v"(w[k][4].y), "+v"(w[k][4].z), "+v"(w[k][4].w),
                       "+v"(w[k][5].x), "+v"(w[k][5].y), "+v"(w[k][5].z), "+v"(w[k][5].w));

  __syncthreads();

  const int s_base = chunk * TOK_PER_BLOCK + wave * TOK_PER_WAVE;
  // wave-uniform skip: this wave's 8 tokens are all discarded downstream
  if (s_base <= lim) {
    // prefetch all 8 tokens (24 independent 1-KiB wave loads in flight)
    const float4* x4 = (const float4*)(lhs + ((size_t)b * S_ + s_base) * H_);
    float4 x[TOK_PER_WAVE][3];
#pragma unroll
    for (int t = 0; t < TOK_PER_WAVE; ++t) {
      x[t][0] = x4[t * 192 + lane];
      x[t][1] = x4[t * 192 + 64 + lane];
      x[t][2] = x4[t * 192 + 128 + lane];
    }

    float racc[C_] = {0.f, 0.f, 0.f, 0.f, 0.f, 0.f};
    int cur_seg = N_;  // sentinel: nothing pending
#pragma unroll
    for (int t = 0; t < TOK_PER_WAVE; ++t) {
      const int s = s_base + t;
      // segment id = count of boundaries < s (wave-uniform)
      const int seg = (int)__popcll(__ballot(stb_l < s));
      if (seg != cur_seg) {  // rare: ~1.4 times per wave
        if (cur_seg < N_) {
#pragma unroll
          for (int c = 0; c < C_; ++c)
            atomicAdd(&acc[(cur_seg * C_ + c) * 64 + lane], racc[c]);
        }
#pragma unroll
        for (int c = 0; c < C_; ++c) racc[c] = 0.f;
        cur_seg = seg;
      }
      // tokens past the last boundary have seg==24; never flushed -> ignored
#pragma unroll
      for (int k = 0; k < 3; ++k)
#pragma unroll
        for (int c = 0; c < C_; ++c)
          racc[c] += x[t][k].x * w[k][c].x + x[t][k].y * w[k][c].y +
                     x[t][k].z * w[k][c].z + x[t][k].w * w[k][c].w;
    }
    if (cur_seg < N_) {
#pragma unroll
      for (int c = 0; c < C_; ++c)
        atomicAdd(&acc[(cur_seg * C_ + c) * 64 + lane], racc[c]);
    }
  }

  __syncthreads();

  // block reduce: 144 threads each sum 64 lane-partials (skewed: conflict-free),
  // publish with device-scope atomicExch (coherent point, cross-XCD safe)
  if (tid < NC) {
    float v = 0.f;
    const int base = tid * 64;
#pragma unroll 8
    for (int i = 0; i < 64; ++i) v += acc[base + ((i + tid) & 63)];
    atomicExch(&ws[(size_t)blockIdx.x * NC + tid], v);
  }

  __syncthreads();  // all 144 atomicExch issued by this block are complete
  if (tid == 0) s_old = atomicAdd(&g_cnt[b], 1);
  __syncthreads();

  if (s_old == CHUNKS - 1) {  // this block is the last arrival for batch b
    if (tid < NC) {
      float* base = ws + (size_t)b * CHUNKS * NC + tid;
      float ssum = 0.f;
#pragma unroll
      for (int k = 0; k < CHUNKS; ++k)
        ssum += atomicAdd(&base[k * NC], 0.0f);  // coherent RMW reads
      const int c = tid % C_;
      const int j = tid / C_;
      const int end = st[b * N_ + j];
      const int prev = (j == 0) ? -1 : st[b * N_ + j - 1];
      const float logit = ssum / (float)(end - prev) + bias[c];
      float p = 1.0f / (1.0f + expf(-logit));
      if (end > 500) {
        const float cl = (c < 3) ? 0.1f : (c == 3 ? 0.3f : (c == 4 ? 0.8f : 0.01f));
        const float cm = (c < 3) ? 0.1f : (c == 3 ? 0.8f : (c == 4 ? 0.3f : 0.01f));
        p = (j == N_ - 1) ? cl : cm;
      }
      out[b * NC + tid] = p;
    }
    if (tid == 0) atomicExch(&g_cnt[b], 0);  // re-arm for the next launch
  }
}

extern "C" void kernel_launch(void* const* d_in, const int* in_sizes, int n_in,
                              void* d_out, int out_size, void* d_ws, size_t ws_size,
                              hipStream_t stream) {
  const float* lhs  = (const float*)d_in[0];  // [B,S,H] fp32
  const int*   st   = (const int*)d_in[1];    // [B,N] int32
  const float* W    = (const float*)d_in[2];  // [C,H] fp32
  const float* bias = (const float*)d_in[3];  // [C] fp32

  // needs B_*CHUNKS*NC*4 = 589824 B of workspace for partials
  seg_proj_fused<<<B_ * CHUNKS, 256, 0, stream>>>(
      lhs, st, W, bias, (float*)d_ws, (float*)d_out);
}

// Round 6
// 153.860 us; speedup vs baseline: 1.0120x; 1.0120x over previous
//
#include <hip/hip_runtime.h>
#include <math.h>

#define B_ 64
#define S_ 512
#define N_ 24
#define H_ 768
#define C_ 6
#define CHUNKS 8                         // blocks per batch
#define TOK_PER_BLOCK (S_ / CHUNKS)      // 64 tokens per block
#define TOK_PER_WAVE (TOK_PER_BLOCK / 4) // 16 tokens per wave (two 8-token halves)
#define NC (N_ * C_)                     // 144

// Arrival counters for the last-block-per-batch finalize. Zero-initialized at
// module load; the finalizing block re-arms its counter to 0 every launch, so
// the protocol survives graph replay. Lives in __device__ memory: the harness's
// workspace poison cannot touch it.
__device__ int g_cnt[B_];

// Best measured configuration (round 4: 152.68us total). One fused dispatch,
// 512 blocks (256 CU x 2 resident, zero tail quantization). Per block: stream
// 64 tokens with the proven 112-VGPR inner loop (register-pinned W fragment,
// 24-deep float4 prefetch per 8-token half, ballot segment-id, LDS
// lane-partial accumulators), reduce to 144 partials, publish via
// device-scope atomicExch, count arrivals; the 8th block of each batch reads
// the partials back with coherent atomicAdd(p,0) reads and finalizes.
// DO NOT tighten the occupancy bound: this loop needs ~112 VGPRs; any cap
// below that spills x[8][3] to scratch (round 2: 290us, round 3: 75us).
// DO NOT raise CHUNKS with this fused tail: the arrival-wait + publish tail
// scales with CHUNKS and ate the oversubscription gain (round 5: 155.7us).
__global__ __launch_bounds__(256, 2) void seg_proj_fused(
    const float* __restrict__ lhs, const int* __restrict__ st,
    const float* __restrict__ W, const float* __restrict__ bias,
    float* __restrict__ ws, float* __restrict__ out) {
  __shared__ float acc[NC * 64];  // 36 KB
  __shared__ int s_old;
  const int tid = threadIdx.x;
  const int lane = tid & 63;
  const int wave = tid >> 6;
  const int b = blockIdx.x >> 3;       // CHUNKS == 8
  const int chunk = blockIdx.x & 7;

  // zero LDS accumulators (2304 float4s / 256 threads = 9 each)
  float4* accv = (float4*)acc;
#pragma unroll
  for (int i = 0; i < 9; ++i)
    accv[i * 256 + tid] = make_float4(0.f, 0.f, 0.f, 0.f);

  // boundaries resident in lanes (sentinel for lanes >= 24)
  int stb_l = (lane < N_) ? st[b * N_ + lane] : 0x7fffffff;
  // tokens s > min(last_boundary, 500) are provably discarded downstream:
  //   s > last -> past the final segment (never flushed);
  //   s > 500  -> its segment has end >= s > 500 -> override in finalize.
  // Non-overridden segments have end <= min(last,500), so every token they
  // need satisfies s <= lim and its half-tile is never skipped.
  const int last = __shfl(stb_l, N_ - 1);
  const int lim = last > 500 ? 500 : last;

  // W fragment: lane holds W[c][k*256 + lane*4 .. +3], k=0..2, c=0..5 (72 VGPRs)
  const float4* W4 = (const float4*)W;
  float4 w[3][C_];
#pragma unroll
  for (int k = 0; k < 3; ++k)
#pragma unroll
    for (int c = 0; c < C_; ++c)
      w[k][c] = W4[c * (H_ / 4) + k * 64 + lane];
  // pin: forbid rematerialization of the W loads
#pragma unroll
  for (int k = 0; k < 3; ++k)
    asm volatile("" : "+v"(w[k][0].x), "+v"(w[k][0].y), "+v"(w[k][0].z), "+v"(w[k][0].w),
                       "+v"(w[k][1].x), "+v"(w[k][1].y), "+v"(w[k][1].z), "+v"(w[k][1].w),
                       "+v"(w[k][2].x), "+v"(w[k][2].y), "+v"(w[k][2].z), "+v"(w[k][2].w),
                       "+v"(w[k][3].x), "+v"(w[k][3].y), "+v"(w[k][3].z), "+v"(w[k][3].w),
                       "+v"(w[k][4].x), "+v"(w[k][4].y), "+v"(w[k][4].z), "+v"(w[k][4].w),
                       "+v"(w[k][5].x), "+v"(w[k][5].y), "+v"(w[k][5].z), "+v"(w[k][5].w));

  __syncthreads();

  const int s_base = chunk * TOK_PER_BLOCK + wave * TOK_PER_WAVE;
  const float4* x4 = (const float4*)(lhs + ((size_t)b * S_ + s_base) * H_);

  float racc[C_] = {0.f, 0.f, 0.f, 0.f, 0.f, 0.f};
  int cur_seg = N_;  // sentinel: nothing pending
#pragma unroll 1     // do NOT unroll: x[8][3] + w[3][6] must fit under 256 VGPRs
  for (int h = 0; h < 2; ++h) {
    const int hb = s_base + h * 8;
    if (hb <= lim) {  // wave-uniform skip of provably-discarded 8-token halves
      // prefetch 8 tokens (24 independent 1-KiB wave loads in flight)
      float4 x[8][3];
#pragma unroll
      for (int t = 0; t < 8; ++t) {
        const int tt = h * 8 + t;
        x[t][0] = x4[tt * 192 + lane];
        x[t][1] = x4[tt * 192 + 64 + lane];
        x[t][2] = x4[tt * 192 + 128 + lane];
      }
#pragma unroll
      for (int t = 0; t < 8; ++t) {
        const int s = hb + t;
        // segment id = count of boundaries < s (wave-uniform)
        const int seg = (int)__popcll(__ballot(stb_l < s));
        if (seg != cur_seg) {  // rare: ~1-2 times per wave
          if (cur_seg < N_) {
#pragma unroll
            for (int c = 0; c < C_; ++c)
              atomicAdd(&acc[(cur_seg * C_ + c) * 64 + lane], racc[c]);
          }
#pragma unroll
          for (int c = 0; c < C_; ++c) racc[c] = 0.f;
          cur_seg = seg;
        }
        // tokens past the last boundary have seg==24; never flushed -> ignored
#pragma unroll
        for (int k = 0; k < 3; ++k)
#pragma unroll
          for (int c = 0; c < C_; ++c)
            racc[c] += x[t][k].x * w[k][c].x + x[t][k].y * w[k][c].y +
                       x[t][k].z * w[k][c].z + x[t][k].w * w[k][c].w;
      }
    }
  }
  if (cur_seg < N_) {
#pragma unroll
    for (int c = 0; c < C_; ++c)
      atomicAdd(&acc[(cur_seg * C_ + c) * 64 + lane], racc[c]);
  }

  __syncthreads();

  // block reduce: 144 threads each sum 64 lane-partials (skewed: conflict-free),
  // publish with device-scope atomicExch (coherent point, cross-XCD safe)
  if (tid < NC) {
    float v = 0.f;
    const int base = tid * 64;
#pragma unroll 8
    for (int i = 0; i < 64; ++i) v += acc[base + ((i + tid) & 63)];
    atomicExch(&ws[(size_t)blockIdx.x * NC + tid], v);
  }

  __syncthreads();  // all 144 atomicExch issued by this block are complete
  if (tid == 0) s_old = atomicAdd(&g_cnt[b], 1);
  __syncthreads();

  if (s_old == CHUNKS - 1) {  // this block is the last arrival for batch b
    if (tid < NC) {
      float* base = ws + (size_t)b * CHUNKS * NC + tid;
      float ssum = 0.f;
#pragma unroll
      for (int k = 0; k < CHUNKS; ++k)
        ssum += atomicAdd(&base[k * NC], 0.0f);  // coherent RMW reads
      const int c = tid % C_;
      const int j = tid / C_;
      const int end = st[b * N_ + j];
      const int prev = (j == 0) ? -1 : st[b * N_ + j - 1];
      const float logit = ssum / (float)(end - prev) + bias[c];
      float p = 1.0f / (1.0f + expf(-logit));
      if (end > 500) {
        const float cl = (c < 3) ? 0.1f : (c == 3 ? 0.3f : (c == 4 ? 0.8f : 0.01f));
        const float cm = (c < 3) ? 0.1f : (c == 3 ? 0.8f : (c == 4 ? 0.3f : 0.01f));
        p = (j == N_ - 1) ? cl : cm;
      }
      out[b * NC + tid] = p;
    }
    if (tid == 0) atomicExch(&g_cnt[b], 0);  // re-arm for the next launch
  }
}

extern "C" void kernel_launch(void* const* d_in, const int* in_sizes, int n_in,
                              void* d_out, int out_size, void* d_ws, size_t ws_size,
                              hipStream_t stream) {
  const float* lhs  = (const float*)d_in[0];  // [B,S,H] fp32
  const int*   st   = (const int*)d_in[1];    // [B,N] int32
  const float* W    = (const float*)d_in[2];  // [C,H] fp32
  const float* bias = (const float*)d_in[3];  // [C] fp32

  // needs B_*CHUNKS*NC*4 = 294912 B of workspace for partials
  seg_proj_fused<<<B_ * CHUNKS, 256, 0, stream>>>(
      lhs, st, W, bias, (float*)d_ws, (float*)d_out);
}